// Round 1
// 477.085 us; speedup vs baseline: 1.0627x; 1.0627x over previous
//
#include <hip/hip_runtime.h>
#include <string.h>

// RuleFilter: out[0] = logits[0]; out[i] = logits[i] * mask_table[argmax(out[i-1])]
// logits: (L=128, N=4096, V=128) fp32, mask_table: (128,128) fp32 {0,1}.
// One wave per sequence n; lane holds vocab elems {2*lane, 2*lane+1}.
//
// R1 change: the serial chain was eating a full HBM round-trip per row
// (VGPR prefetch ring collapsed at VGPR_Count=32; latency-bound at 23% BW).
// Replace it with HARDWARE async prefetch: global_load_lds into a 16-slot
// per-wave LDS ring, drained by a hand-counted s_waitcnt vmcnt(28) (never 0).
// The compiler doesn't track gl_lds->LDS deps, so it adds no conservative
// waits; ~9-10 rows stay in flight per wave independent of regalloc.

constexpr int V = 128;
constexpr int L = 128;
constexpr int N = 4096;
constexpr int SLOTS = 16;   // per-wave LDS ring depth (rows of 512 B)
constexpr int DIST  = 15;   // issue row i+DIST at end of iter i -> slot (i-1)&15 (freed last iter)
// vmcnt bookkeeping: 3 vmem ops per iter (2 gl_lds + 1 store), issue AFTER consume.
// ops newer than row-i's load pair: 30 (i=0), 28+i (1<=i<=15), 42 (steady).
// A uniform wait N must satisfy N <= min(newer) = 29 -> use 28 (1 op of margin).
constexpr int WAITN = 28;

// Wave-wide max of x (all 64 lanes active), result broadcast to all lanes.
__device__ __forceinline__ float wave_max_dpp(float x) {
    int v = __float_as_int(x);
    const int ninf = __float_as_int(-__builtin_inff());
#define RF_STEP(ctrl)                                                          \
    {                                                                          \
        int s = __builtin_amdgcn_update_dpp(ninf, v, ctrl, 0xf, 0xf, false);   \
        v = __float_as_int(fmaxf(__int_as_float(v), __int_as_float(s)));       \
    }
    RF_STEP(0x111)  // row_shr:1
    RF_STEP(0x112)  // row_shr:2
    RF_STEP(0x114)  // row_shr:4
    RF_STEP(0x118)  // row_shr:8  -> lane 15 of each row16 has row max
    RF_STEP(0x142)  // row_bcast:15 -> lane31 = max(0..31), lane63 = max(32..63)
    RF_STEP(0x143)  // row_bcast:31 -> lane63 = max(all)
#undef RF_STEP
    return __int_as_float(__builtin_amdgcn_readlane(v, 63));
}

// argmax over the 128 values {f.x@2*lane, f.y@2*lane+1}; ties -> lowest index.
__device__ __forceinline__ int wave_argmax(float2 f) {
    const float bv = wave_max_dpp(fmaxf(f.x, f.y));
    unsigned long long b0 = __ballot(f.x == bv);
    unsigned long long b1 = __ballot(f.y == bv);
    int i0 = __ffsll(b0);  // 1-based, 0 if none
    int i1 = __ffsll(b1);
    int c0 = i0 ? (i0 - 1) * 2 : (1 << 30);
    int c1 = i1 ? (i1 - 1) * 2 + 1 : (1 << 30);
    return min(c0, c1);
}

// 8-way dynamic register select (j is wave-uniform; 7 cndmask/cselect ops).
__device__ __forceinline__ unsigned sel8(const unsigned* t, int j) {
    unsigned a0 = (j & 1) ? t[1] : t[0];
    unsigned a1 = (j & 1) ? t[3] : t[2];
    unsigned a2 = (j & 1) ? t[5] : t[4];
    unsigned a3 = (j & 1) ? t[7] : t[6];
    unsigned b0 = (j & 2) ? a1 : a0;
    unsigned b1 = (j & 2) ? a3 : a2;
    return (j & 4) ? b1 : b0;
}

typedef __attribute__((address_space(1))) const float* gas1_cfp;
typedef __attribute__((address_space(3))) float*       las3_fp;

// async global->LDS, 4 B per lane (64 lanes = 256 B). LDS dest is
// wave-uniform base + lane*4 (HW rule); global src is per-lane.
__device__ __forceinline__ void stage_word(const float* g, float* l) {
    __builtin_amdgcn_global_load_lds((gas1_cfp)g, (las3_fp)l, 4, 0, 0);
}

__global__ __launch_bounds__(256, 4) void rule_filter_kernel(
    const float* __restrict__ logits,      // (L, N, V)
    const float* __restrict__ mask_table,  // (V, V)
    float* __restrict__ out)               // (L, N, V)
{
    __shared__ float ring[4][SLOTS][V];    // 32 KiB/block; 4 blocks/CU = 128 KiB <= 160

    const int wave = threadIdx.x >> 6;  // 0..3
    const int lane = threadIdx.x & 63;  // 0..63
    const int n    = (blockIdx.x << 2) + wave;

    const size_t rstride = (size_t)N * V;
    const float* seq     = logits + (size_t)n * V;          // + i*rstride
    const size_t obase   = (size_t)n * V + (size_t)(lane * 2);

    // Per-lane mask table: tbl[j] bit(2r..2r+1) = mask_table[16j+r][2*lane .. 2*lane+1]
    unsigned tbl[8];
#pragma unroll 1
    for (int j = 0; j < 8; ++j) {
        unsigned acc = 0;
#pragma unroll
        for (int r = 0; r < 16; ++r) {
            const int p = j * 16 + r;
            float2 mv = *(const float2*)(mask_table + (size_t)p * V + lane * 2);
            acc |= ((mv.x != 0.0f ? 1u : 0u) | (mv.y != 0.0f ? 2u : 0u)) << (2 * r);
        }
        tbl[j] = acc;
    }
    // Drain the table loads so the vmcnt bookkeeping below is exact.
    asm volatile("s_waitcnt vmcnt(0)" ::: "memory");

    float* const my = &ring[wave][0][0];

    // Prologue: stage rows 0..15 into slots 0..15 (2 gl_lds each = 32 ops).
#pragma unroll 1
    for (int r = 0; r < SLOTS; ++r) {
        const float* rp = seq + (size_t)r * rstride;
        float* lp = my + r * V;
        stage_word(rp + lane,      lp);
        stage_word(rp + 64 + lane, lp + 64);
    }

    auto st = [&](int i, float2 v) {
        long long bits;
        memcpy(&bits, &v, 8);
        __builtin_nontemporal_store(bits, (long long*)(out + (size_t)i * rstride + obase));
    };

    // ---- row 0: pass-through ----
    asm volatile("s_waitcnt vmcnt(" "28" ")" ::: "memory");  // newer-than-row0 = 30 >= 28: safe
    float2 c0 = *(const float2*)(my + 2 * lane);
    st(0, c0);
    int prev = wave_argmax(c0);

    for (int i = 1; i < L; ++i) {
        // Wait until row i's pair has landed in LDS (in-order vmcnt decrement;
        // ops newer than row i's pair >= 28 at every i, so vmcnt(28) suffices
        // and still leaves ~9 rows of prefetch in flight).
        asm volatile("s_waitcnt vmcnt(28)" ::: "memory");
        float2 c = *(const float2*)(my + (i & (SLOTS - 1)) * V + 2 * lane);

        const unsigned word  = sel8(tbl, prev >> 4);
        const unsigned fbits = (word >> ((prev & 15) * 2)) & 3u;
        float2 f;
        f.x = (fbits & 1u) ? c.x : 0.0f;
        f.y = (fbits & 2u) ? c.y : 0.0f;

        st(i, f);
        prev = wave_argmax(f);

        // Issue next prefetch AFTER consume: slot (i+15)&15 == (i-1)&15 was
        // consumed last iteration. Tail clamps re-stage row 127 (same bytes,
        // benign) to keep the per-iteration vmem-op count uniform at 3.
        const int pf = (i + DIST < L) ? (i + DIST) : (L - 1);
        const float* rp = seq + (size_t)pf * rstride;
        float* lp = my + (pf & (SLOTS - 1)) * V;
        stage_word(rp + lane,      lp);
        stage_word(rp + 64 + lane, lp + 64);
    }
}

extern "C" void kernel_launch(void* const* d_in, const int* in_sizes, int n_in,
                              void* d_out, int out_size, void* d_ws, size_t ws_size,
                              hipStream_t stream) {
    const float* logits     = (const float*)d_in[0];  // (L, N, V) fp32
    const float* mask_table = (const float*)d_in[1];  // (V, V) fp32
    float* out              = (float*)d_out;          // (L, N, V) fp32

    dim3 grid(N / 4);  // 4 sequences (waves) per 256-thread block
    dim3 block(256);
    rule_filter_kernel<<<grid, block, 0, stream>>>(logits, mask_table, out);
}

// Round 3
// 450.119 us; speedup vs baseline: 1.1264x; 1.0599x over previous
//
#include <hip/hip_runtime.h>

// RuleFilter: out[0] = logits[0]; out[i] = logits[i] * mask_table[argmax(out[i-1])]
// logits: (L=128, N=4096, V=128) fp32, mask_table: (128,128) fp32 {0,1}.
// One wave per sequence n; lane holds vocab elems {2*lane, 2*lane+1}.
//
// R3 = R2 with the saddr fix: base pointers are wave-uniform but derived from
// threadIdx, so divergence analysis rejects an "s" constraint. Launder through
// readfirstlane (HK's SGPR-hoist idiom) so the global_{load,store} saddr forms
// get a real SGPR pair. Pipeline: register ring, exact per-step
// s_waitcnt vmcnt(N) (steady N=30, never 0), ordering via register ties.

constexpr int V = 128;
constexpr int L = 128;
constexpr int N = 4096;
constexpr int D = 16;  // register ring depth (rows in flight)
constexpr unsigned ROWB = (unsigned)N * V * 4;  // 2 MiB: byte stride between rows

typedef __attribute__((ext_vector_type(2))) float f32x2;

// Wave-wide max of x (all 64 lanes active), result broadcast to all lanes.
__device__ __forceinline__ float wave_max_dpp(float x) {
    int v = __float_as_int(x);
    const int ninf = __float_as_int(-__builtin_inff());
#define RF_STEP(ctrl)                                                          \
    {                                                                          \
        int s = __builtin_amdgcn_update_dpp(ninf, v, ctrl, 0xf, 0xf, false);   \
        v = __float_as_int(fmaxf(__int_as_float(v), __int_as_float(s)));       \
    }
    RF_STEP(0x111)  // row_shr:1
    RF_STEP(0x112)  // row_shr:2
    RF_STEP(0x114)  // row_shr:4
    RF_STEP(0x118)  // row_shr:8  -> lane 15 of each row16 has row max
    RF_STEP(0x142)  // row_bcast:15 -> lane31 = max(0..31), lane63 = max(32..63)
    RF_STEP(0x143)  // row_bcast:31 -> lane63 = max(all)
#undef RF_STEP
    return __int_as_float(__builtin_amdgcn_readlane(v, 63));
}

// argmax over the 128 values {f.x@2*lane, f.y@2*lane+1}; ties -> lowest index.
__device__ __forceinline__ int wave_argmax(f32x2 f) {
    const float bv = wave_max_dpp(fmaxf(f.x, f.y));
    unsigned long long b0 = __ballot(f.x == bv);
    unsigned long long b1 = __ballot(f.y == bv);
    int i0 = __ffsll(b0);  // 1-based, 0 if none
    int i1 = __ffsll(b1);
    int c0 = i0 ? (i0 - 1) * 2 : (1 << 30);
    int c1 = i1 ? (i1 - 1) * 2 + 1 : (1 << 30);
    return min(c0, c1);
}

// 8-way dynamic register select (j is wave-uniform; 7 cndmask/cselect ops).
__device__ __forceinline__ unsigned sel8(const unsigned* t, int j) {
    unsigned a0 = (j & 1) ? t[1] : t[0];
    unsigned a1 = (j & 1) ? t[3] : t[2];
    unsigned a2 = (j & 1) ? t[5] : t[4];
    unsigned a3 = (j & 1) ? t[7] : t[6];
    unsigned b0 = (j & 2) ? a1 : a0;
    unsigned b1 = (j & 2) ? a3 : a2;
    return (j & 4) ? b1 : b0;
}

// Wave-uniform pointer -> value the compiler KNOWS is uniform (SGPR-allocatable).
__device__ __forceinline__ unsigned long long uniform_u64(const void* p) {
    unsigned long long x = (unsigned long long)p;
    unsigned lo = __builtin_amdgcn_readfirstlane((unsigned)x);
    unsigned hi = __builtin_amdgcn_readfirstlane((unsigned)(x >> 32));
    return ((unsigned long long)hi << 32) | lo;
}

// One fully-unrolled pipeline step. All indices compile-time; ring/fbuf live
// entirely in VGPRs (SROA: every access has a constant index).
template <int I>
struct Step {
    static __device__ __forceinline__ void run(f32x2* ring, f32x2* fbuf,
                                               const unsigned* tbl, int& prev,
                                               unsigned long long lbase,
                                               unsigned long long obase,
                                               unsigned laneoff) {
        // Exact count of vmem ops issued after this slot's load:
        //   prologue region: 15+I ; steady: 30 ; tail (loads exhausted): 15+(127-I)
        constexpr int NW = (I <= 15) ? (15 + I) : ((I <= L - D - 1) ? 30 : (15 + (L - 1 - I)));
        constexpr int s  = I & (D - 1);

        // Wait until row I's load retired. Ties:
        //  %0 ring[s]  -> consumers below are data-ordered after the wait
        //  %1 fbuf[s]  -> keeps the 16-iter-old store's data reg alive until
        //                 this wait (which provably retires that store)
        asm volatile("s_waitcnt vmcnt(%c2)"
                     : "+v"(ring[s])
                     : "v"(fbuf[s]), "i"(NW));

        f32x2 c = ring[s];
        f32x2 f;
        if (I == 0) {
            f = c;  // row 0 passes through unfiltered
        } else {
            const unsigned word  = sel8(tbl, prev >> 4);
            const unsigned fbits = (word >> ((prev & 15) * 2)) & 3u;
            f.x = (fbits & 1u) ? c.x : 0.0f;
            f.y = (fbits & 2u) ? c.y : 0.0f;
        }
        fbuf[s] = f;

        {
            unsigned voff = (unsigned)I * ROWB + laneoff;
            asm volatile("global_store_dwordx2 %0, %1, %2 nt"
                         :
                         : "v"(voff), "v"(fbuf[s]), "s"(obase));
        }

        prev = wave_argmax(f);

        if constexpr (I + D < L) {
            unsigned voff = (unsigned)(I + D) * ROWB + laneoff;
            asm volatile("global_load_dwordx2 %0, %1, %2"
                         : "=&v"(ring[s])
                         : "v"(voff), "s"(lbase));
        }

        Step<I + 1>::run(ring, fbuf, tbl, prev, lbase, obase, laneoff);
    }
};
template <>
struct Step<L> {
    static __device__ __forceinline__ void run(f32x2*, f32x2*, const unsigned*,
                                               int&, unsigned long long,
                                               unsigned long long, unsigned) {}
};

__global__ __launch_bounds__(256, 4) void rule_filter_kernel(
    const float* __restrict__ logits,      // (L, N, V)
    const float* __restrict__ mask_table,  // (V, V)
    float* __restrict__ out)               // (L, N, V)
{
    const int wave = threadIdx.x >> 6;  // 0..3
    const int lane = threadIdx.x & 63;  // 0..63
    const int n    = (blockIdx.x << 2) + wave;

    // Wave-uniform base pointers, laundered to SGPR-provable uniformity.
    const unsigned long long lbase = uniform_u64(logits + (size_t)n * V);
    const unsigned long long obase = uniform_u64(out    + (size_t)n * V);
    const unsigned laneoff = (unsigned)lane * 8;  // dwordx2 per lane

    // Per-lane mask table: tbl[j] bit(2r..2r+1) = mask_table[16j+r][2*lane..2*lane+1]
    unsigned tbl[8];
#pragma unroll 1
    for (int j = 0; j < 8; ++j) {
        unsigned acc = 0;
#pragma unroll
        for (int r = 0; r < 16; ++r) {
            const int p = j * 16 + r;
            float2 mv = *(const float2*)(mask_table + (size_t)p * V + lane * 2);
            acc |= ((mv.x != 0.0f ? 1u : 0u) | (mv.y != 0.0f ? 2u : 0u)) << (2 * r);
        }
        tbl[j] = acc;
    }
    // Drain table loads so the hand-counted vmcnt bookkeeping is exact.
    asm volatile("s_waitcnt vmcnt(0)" ::: "memory");

    f32x2 ring[D];
    f32x2 fbuf[D];
#pragma unroll
    for (int r = 0; r < D; ++r) { fbuf[r].x = 0.0f; fbuf[r].y = 0.0f; }

    // Prologue: issue loads for rows 0..15 (in order; vmcnt ops 1..16).
#pragma unroll
    for (int r = 0; r < D; ++r) {
        unsigned voff = (unsigned)r * ROWB + laneoff;
        asm volatile("global_load_dwordx2 %0, %1, %2"
                     : "=&v"(ring[r])
                     : "v"(voff), "s"(lbase));
    }

    int prev = 0;
    Step<0>::run(ring, fbuf, tbl, prev, lbase, obase, laneoff);
}

extern "C" void kernel_launch(void* const* d_in, const int* in_sizes, int n_in,
                              void* d_out, int out_size, void* d_ws, size_t ws_size,
                              hipStream_t stream) {
    const float* logits     = (const float*)d_in[0];  // (L, N, V) fp32
    const float* mask_table = (const float*)d_in[1];  // (V, V) fp32
    float* out              = (float*)d_out;          // (L, N, V) fp32

    dim3 grid(N / 4);  // 4 sequences (waves) per 256-thread block
    dim3 block(256);
    rule_filter_kernel<<<grid, block, 0, stream>>>(logits, mask_table, out);
}

// Round 4
// 439.126 us; speedup vs baseline: 1.1546x; 1.0250x over previous
//
#include <hip/hip_runtime.h>

// RuleFilter: out[0] = logits[0]; out[i] = logits[i] * mask_table[argmax(out[i-1])]
// logits: (L=128, N=4096, V=128) fp32, mask_table: (128,128) fp32 {0,1}.
// One wave per sequence n; lane holds vocab elems {2*lane, 2*lane+1}.
//
// R4: R0/R1/R3 all plateaued at ~2.4 TB/s with three different load-pipeline
// structures -> the common factor is the stores. vmcnt retires IN ORDER, so
// the per-step "is my load back?" wait also waits for the 16-step-old
// NON-TEMPORAL store's ack, which comes from the HBM write path (multi-us
// under 1.6 TB/s write load). iter_time ~ store_ack/slack ~ 650ns = observed.
// Fix: drop `nt` (stores ack at L2, ~300cy) and deepen the ring to D=20.
// Pipeline: all-asm vmem (compiler can't see it -> no conservative waits),
// exact per-step s_waitcnt vmcnt(N) (steady N=2D-2=38, never 0), ordering
// via register ties (no "memory" clobbers in the loop).

constexpr int V = 128;
constexpr int L = 128;
constexpr int N = 4096;
constexpr int D = 20;  // register ring depth (rows in flight); % D is constexpr
constexpr unsigned ROWB = (unsigned)N * V * 4;  // 2 MiB: byte stride between rows

typedef __attribute__((ext_vector_type(2))) float f32x2;

// Wave-wide max of x (all 64 lanes active), result broadcast to all lanes.
__device__ __forceinline__ float wave_max_dpp(float x) {
    int v = __float_as_int(x);
    const int ninf = __float_as_int(-__builtin_inff());
#define RF_STEP(ctrl)                                                          \
    {                                                                          \
        int s = __builtin_amdgcn_update_dpp(ninf, v, ctrl, 0xf, 0xf, false);   \
        v = __float_as_int(fmaxf(__int_as_float(v), __int_as_float(s)));       \
    }
    RF_STEP(0x111)  // row_shr:1
    RF_STEP(0x112)  // row_shr:2
    RF_STEP(0x114)  // row_shr:4
    RF_STEP(0x118)  // row_shr:8  -> lane 15 of each row16 has row max
    RF_STEP(0x142)  // row_bcast:15 -> lane31 = max(0..31), lane63 = max(32..63)
    RF_STEP(0x143)  // row_bcast:31 -> lane63 = max(all)
#undef RF_STEP
    return __int_as_float(__builtin_amdgcn_readlane(v, 63));
}

// argmax over the 128 values {f.x@2*lane, f.y@2*lane+1}; ties -> lowest index.
__device__ __forceinline__ int wave_argmax(f32x2 f) {
    const float bv = wave_max_dpp(fmaxf(f.x, f.y));
    unsigned long long b0 = __ballot(f.x == bv);
    unsigned long long b1 = __ballot(f.y == bv);
    int i0 = __ffsll(b0);  // 1-based, 0 if none
    int i1 = __ffsll(b1);
    int c0 = i0 ? (i0 - 1) * 2 : (1 << 30);
    int c1 = i1 ? (i1 - 1) * 2 + 1 : (1 << 30);
    return min(c0, c1);
}

// 8-way dynamic register select (j is wave-uniform; 7 cndmask/cselect ops).
__device__ __forceinline__ unsigned sel8(const unsigned* t, int j) {
    unsigned a0 = (j & 1) ? t[1] : t[0];
    unsigned a1 = (j & 1) ? t[3] : t[2];
    unsigned a2 = (j & 1) ? t[5] : t[4];
    unsigned a3 = (j & 1) ? t[7] : t[6];
    unsigned b0 = (j & 2) ? a1 : a0;
    unsigned b1 = (j & 2) ? a3 : a2;
    return (j & 4) ? b1 : b0;
}

// Wave-uniform pointer -> value the compiler KNOWS is uniform (SGPR-allocatable).
__device__ __forceinline__ unsigned long long uniform_u64(const void* p) {
    unsigned long long x = (unsigned long long)p;
    unsigned lo = __builtin_amdgcn_readfirstlane((unsigned)x);
    unsigned hi = __builtin_amdgcn_readfirstlane((unsigned)(x >> 32));
    return ((unsigned long long)hi << 32) | lo;
}

// One fully-unrolled pipeline step. All indices compile-time; ring/fbuf live
// entirely in VGPRs (SROA: every access has a constant index).
template <int I>
struct Step {
    static __device__ __forceinline__ void run(f32x2* ring, f32x2* fbuf,
                                               const unsigned* tbl, int& prev,
                                               unsigned long long lbase,
                                               unsigned long long obase,
                                               unsigned laneoff) {
        // Exact count of vmem ops issued after this slot's load (issue order
        // per step: wait, store S_I, load L_{I+D}):
        //   prologue region (I<=D-1): D-1+I
        //   steady (I<=L-D-1):        2D-2
        //   tail (loads exhausted):   D-1+(L-1-I)
        constexpr int NW = (I <= D - 1) ? (D - 1 + I)
                         : ((I <= L - D - 1) ? (2 * D - 2) : (D - 1 + (L - 1 - I)));
        constexpr int s  = I % D;

        // Wait until row I's load retired. Ties:
        //  %0 ring[s]  -> consumers below are data-ordered after the wait
        //  %1 fbuf[s]  -> keeps the D-iter-old store's data reg alive until
        //                 this wait (which provably retires that store)
        asm volatile("s_waitcnt vmcnt(%c2)"
                     : "+v"(ring[s])
                     : "v"(fbuf[s]), "i"(NW));

        f32x2 c = ring[s];
        f32x2 f;
        if (I == 0) {
            f = c;  // row 0 passes through unfiltered
        } else {
            const unsigned word  = sel8(tbl, prev >> 4);
            const unsigned fbits = (word >> ((prev & 15) * 2)) & 3u;
            f.x = (fbits & 1u) ? c.x : 0.0f;
            f.y = (fbits & 2u) ? c.y : 0.0f;
        }
        fbuf[s] = f;

        {
            unsigned voff = (unsigned)I * ROWB + laneoff;
            // NO `nt`: store acks at L2 (~300cy) instead of the HBM write
            // queue (multi-us) -> the in-order vmcnt wait stops gating on acks.
            asm volatile("global_store_dwordx2 %0, %1, %2"
                         :
                         : "v"(voff), "v"(fbuf[s]), "s"(obase));
        }

        prev = wave_argmax(f);

        if constexpr (I + D < L) {
            unsigned voff = (unsigned)(I + D) * ROWB + laneoff;
            asm volatile("global_load_dwordx2 %0, %1, %2"
                         : "=&v"(ring[s])
                         : "v"(voff), "s"(lbase));
        }

        Step<I + 1>::run(ring, fbuf, tbl, prev, lbase, obase, laneoff);
    }
};
template <>
struct Step<L> {
    static __device__ __forceinline__ void run(f32x2*, f32x2*, const unsigned*,
                                               int&, unsigned long long,
                                               unsigned long long, unsigned) {}
};

__global__ __launch_bounds__(256, 4) void rule_filter_kernel(
    const float* __restrict__ logits,      // (L, N, V)
    const float* __restrict__ mask_table,  // (V, V)
    float* __restrict__ out)               // (L, N, V)
{
    const int wave = threadIdx.x >> 6;  // 0..3
    const int lane = threadIdx.x & 63;  // 0..63
    const int n    = (blockIdx.x << 2) + wave;

    // Wave-uniform base pointers, laundered to SGPR-provable uniformity.
    const unsigned long long lbase = uniform_u64(logits + (size_t)n * V);
    const unsigned long long obase = uniform_u64(out    + (size_t)n * V);
    const unsigned laneoff = (unsigned)lane * 8;  // dwordx2 per lane

    // Per-lane mask table: tbl[j] bit(2r..2r+1) = mask_table[16j+r][2*lane..2*lane+1]
    unsigned tbl[8];
#pragma unroll 1
    for (int j = 0; j < 8; ++j) {
        unsigned acc = 0;
#pragma unroll
        for (int r = 0; r < 16; ++r) {
            const int p = j * 16 + r;
            float2 mv = *(const float2*)(mask_table + (size_t)p * V + lane * 2);
            acc |= ((mv.x != 0.0f ? 1u : 0u) | (mv.y != 0.0f ? 2u : 0u)) << (2 * r);
        }
        tbl[j] = acc;
    }
    // Drain table loads so the hand-counted vmcnt bookkeeping is exact.
    asm volatile("s_waitcnt vmcnt(0)" ::: "memory");

    f32x2 ring[D];
    f32x2 fbuf[D];
#pragma unroll
    for (int r = 0; r < D; ++r) { fbuf[r].x = 0.0f; fbuf[r].y = 0.0f; }

    // Prologue: issue loads for rows 0..D-1 (in order; vmcnt ops 1..D).
#pragma unroll
    for (int r = 0; r < D; ++r) {
        unsigned voff = (unsigned)r * ROWB + laneoff;
        asm volatile("global_load_dwordx2 %0, %1, %2"
                     : "=&v"(ring[r])
                     : "v"(voff), "s"(lbase));
    }

    int prev = 0;
    Step<0>::run(ring, fbuf, tbl, prev, lbase, obase, laneoff);
}

extern "C" void kernel_launch(void* const* d_in, const int* in_sizes, int n_in,
                              void* d_out, int out_size, void* d_ws, size_t ws_size,
                              hipStream_t stream) {
    const float* logits     = (const float*)d_in[0];  // (L, N, V) fp32
    const float* mask_table = (const float*)d_in[1];  // (V, V) fp32
    float* out              = (float*)d_out;          // (L, N, V) fp32

    dim3 grid(N / 4);  // 4 sequences (waves) per 256-thread block
    dim3 block(256);
    rule_filter_kernel<<<grid, block, 0, stream>>>(logits, mask_table, out);
}